// Round 16
// baseline (132.774 us; speedup 1.0000x reference)
//
#include <hip/hip_runtime.h>
#include <math.h>

#define BB 16
#define C1 64
#define C2 64
#define HH 160
#define WW 160
#define KK 4
#define HID 16
#define EPS 1e-5f
#define HWSZ (HH*WW)          // 25600
#define NPB (BB*HWSZ)         // 409600 per-channel element count

// ws layout (float offsets)
#define WS_AF    1024         // 1024
#define WS_AC    2048         // 1024
#define WS_AS    3072         // 144
#define WS_AW    3216         // 64
#define WS_BIAS  3280         // 1024
#define WS_STATS 4432         // NSLOT*128 = 4096
#define NSLOT    32
#define WS_PART  8704         // 64*40*16 = 40960 pool partials
#define WS_WEFF  53760        // bf16 image: 16 * 4608 uint4 = 294912 floats
#define WS_XBF   348672       // bf16 x image: 64*160*320 uint4 = 13,107,200 floats
#define WS_OBF   13455872     // bf16 conv-out image: 26,214,400 bf16 = 13,107,200 floats
#define WS_NEED_BYTES 106252288ULL   // (WS_OBF + 13107200) * 4

typedef __attribute__((ext_vector_type(8)))  short bf16x8;
typedef __attribute__((ext_vector_type(16))) float f32x16;

__device__ __forceinline__ unsigned short f2bf(float f) {
    unsigned int u = __float_as_uint(f);
    unsigned int r = (u + 0x7FFFu + ((u >> 16) & 1u)) >> 16;
    return (unsigned short)r;
}

__device__ __forceinline__ void gload16(const void* g, void* l) {
    __builtin_amdgcn_global_load_lds(
        (const __attribute__((address_space(1))) unsigned int*)g,
        (__attribute__((address_space(3))) unsigned int*)l, 16, 0, 0);
}

// ---------------- Kernel 0: x -> bf16 channels-last image + pool partials ----------------
__global__ __launch_bounds__(256) void xprep_kernel(const float* __restrict__ x,
                                                    float* __restrict__ ws) {
    __shared__ float lds[10240];        // 2560 float4 granules, 40 KB
    int bcc = blockIdx.y;
    int rg = blockIdx.x;
    int t = threadIdx.x;

    const float* src = x + (size_t)bcc * 16 * HWSZ + (size_t)rg * 4 * WW;
    float4* l4 = (float4*)lds;
    #pragma unroll
    for (int i = 0; i < 10; ++i) {
        int g = i * 256 + t;
        int ch = g / 160, rem = g - ch * 160;
        l4[g] = *(const float4*)(src + (size_t)ch * HWSZ + rem * 4);
    }
    __syncthreads();

    {
        int ch = t >> 4, j = t & 15;
        float s = 0.f;
        #pragma unroll
        for (int m = 0; m < 40; ++m) s += lds[ch * 640 + j + 16 * m];
        #pragma unroll
        for (int o = 8; o > 0; o >>= 1) s += __shfl_down(s, o, 16);
        if (j == 0) ws[WS_PART + ((size_t)bcc * 40 + rg) * 16 + ch] = s;
    }

    uint4* dst = (uint4*)(ws + WS_XBF) + ((size_t)bcc * 160 + rg * 4) * 320;
    #pragma unroll
    for (int i = 0; i < 5; ++i) {
        int u = i * 256 + t;
        int row = u / 320, rem = u - row * 320;
        int col = rem >> 1, p = rem & 1;
        int h = p ^ ((col >> 2) & 1) ^ 1;
        union { uint4 q; unsigned short us[8]; } pk;
        #pragma unroll
        for (int k = 0; k < 8; ++k)
            pk.us[k] = f2bf(lds[(h * 8 + k) * 640 + row * 160 + col]);
        dst[u] = pk.q;
    }
}

// ---------------- Kernel 2: attention MLP (single block) ----------------
__global__ void attn_kernel(float* __restrict__ ws,
    const float* __restrict__ Wfc, const float* __restrict__ gh, const float* __restrict__ bh,
    const float* __restrict__ Wf,  const float* __restrict__ bf,
    const float* __restrict__ Wsm, const float* __restrict__ bs,
    const float* __restrict__ Wc,  const float* __restrict__ bc,
    const float* __restrict__ Ww,  const float* __restrict__ bw,
    const float* __restrict__ bk) {
    __shared__ float ctxs[16][64];
    __shared__ float hs[16][16];
    __shared__ float aw[16][4];
    int t = threadIdx.x;

    #pragma unroll
    for (int q = 0; q < 4; ++q) {
        int idx = t * 4 + q;
        int b = idx >> 6, c1 = idx & 63;
        const float* pp = ws + WS_PART + ((size_t)(b * 4 + (c1 >> 4)) * 40) * 16 + (c1 & 15);
        float s = 0.f;
        #pragma unroll
        for (int rg = 0; rg < 40; ++rg) s += pp[rg * 16];
        ctxs[b][c1] = s * (1.0f / (float)HWSZ);
    }
    __syncthreads();
    {
        int b = t >> 4, j = t & 15;
        const float* wr = Wfc + j * 64;
        float s = 0.f;
        #pragma unroll
        for (int c = 0; c < 64; c++) s += ctxs[b][c] * wr[c];
        hs[b][j] = s;
    }
    __syncthreads();
    if (t < 16) {
        int j = t;
        float mu = 0.f;
        #pragma unroll
        for (int b = 0; b < 16; b++) mu += hs[b][j];
        mu *= (1.f / 16.f);
        float vr = 0.f;
        #pragma unroll
        for (int b = 0; b < 16; b++) { float d = hs[b][j] - mu; vr += d * d; }
        vr *= (1.f / 16.f);
        float sc = gh[j] * rsqrtf(vr + EPS);
        float sh = bh[j] - mu * sc;
        #pragma unroll
        for (int b = 0; b < 16; b++) {
            float v = hs[b][j] * sc + sh;
            hs[b][j] = v > 0.f ? v : 0.f;
        }
    }
    __syncthreads();
    if (t < 16) {
        int b = t;
        float l[4]; float mx = -1e30f;
        #pragma unroll
        for (int k = 0; k < 4; k++) {
            float s = bw[k];
            #pragma unroll
            for (int j = 0; j < 16; j++) s += hs[b][j] * Ww[k * 16 + j];
            l[k] = s; mx = fmaxf(mx, s);
        }
        float den = 0.f;
        #pragma unroll
        for (int k = 0; k < 4; k++) { l[k] = expf(l[k] - mx); den += l[k]; }
        float r = 1.f / den;
        #pragma unroll
        for (int k = 0; k < 4; k++) { float v = l[k] * r; aw[b][k] = v; ws[WS_AW + b * 4 + k] = v; }
    }
    #pragma unroll
    for (int q = 0; q < 4; q++) {
        int idx = t * 4 + q;
        int b = idx >> 6, c2 = idx & 63;
        float sf = bf[c2], sc2 = bc[c2];
        #pragma unroll
        for (int j = 0; j < 16; j++) {
            float hv = hs[b][j];
            sf  += hv * Wf[c2 * 16 + j];
            sc2 += hv * Wc[c2 * 16 + j];
        }
        ws[WS_AF + idx] = 1.f / (1.f + expf(-sf));
        ws[WS_AC + idx] = 1.f / (1.f + expf(-sc2));
    }
    if (t < 144) {
        int b = t / 9, uv = t % 9;
        float s = bs[uv];
        #pragma unroll
        for (int j = 0; j < 16; j++) s += hs[b][j] * Wsm[uv * 16 + j];
        ws[WS_AS + t] = 1.f / (1.f + expf(-s));
    }
    __syncthreads();
    #pragma unroll
    for (int q = 0; q < 4; q++) {
        int idx = t * 4 + q;
        int b = idx >> 6, c2 = idx & 63;
        float s = 0.f;
        #pragma unroll
        for (int k = 0; k < 4; k++) s += aw[b][k] * bk[k * 64 + c2];
        ws[WS_BIAS + idx] = s;
    }
    for (int i = t; i < NSLOT * 128; i += 256) ws[WS_STATS + i] = 0.f;
}

// ---------------- Kernel 3: effective weights -> bf16 image ----------------
__global__ void wprep_kernel(const float* __restrict__ Wk, float* __restrict__ ws) {
    int b = blockIdx.y;
    int tid = blockIdx.x * 256 + threadIdx.x;   // < 4608
    int h = tid & 1;
    int c2 = (tid >> 1) & 63;
    int g = tid >> 7;          // 0..35
    int uv = g % 9;
    int chunk = g / 9;
    const float* awp = ws + WS_AW + b * 4;
    float aw0 = awp[0], aw1 = awp[1], aw2 = awp[2], aw3 = awp[3];
    float af = ws[WS_AF + b * 64 + c2];
    float as_ = ws[WS_AS + b * 9 + uv];
    union { uint4 q; unsigned short u[8]; } pk;
    #pragma unroll
    for (int j = 0; j < 8; ++j) {
        int c1 = chunk * 16 + h * 8 + j;
        const float* wp = Wk + (size_t)(c2 * 64 + c1) * 9 + uv;
        float s = aw0 * wp[0] + aw1 * wp[64 * 64 * 9] + aw2 * wp[2 * 64 * 64 * 9] + aw3 * wp[3 * 64 * 64 * 9];
        float w = s * af * ws[WS_AC + b * 64 + c1] * as_;
        pk.u[j] = f2bf(w);
    }
    int unit = ((chunk * 9 + uv) * 64 + c2) * 2 + (h ^ ((c2 >> 2) & 1));
    ((uint4*)(ws + WS_WEFF))[(size_t)b * 4608 + unit] = pk.q;
}

// ---------------- Kernel 4: MFMA conv — R8 structure, BK=32 (2 phases) ----------------
// Grid 1280: b = id&15 (XCD locality), bx = id>>4 (0..79), 2 output rows.
// 256 thr = 4 waves (rw = wv>>1, c2h = wv&1), acc[5] = 32 c2 x 160 px.
// Each phase stages 2 c1-chunks of x+w (79.1 KB LDS total -> 2 blocks/CU) and
// computes 108 ds_reads + 90 MFMAs per wave in one scheduling scope.
template<int OBF>
__launch_bounds__(256, 2)
__global__ void conv_kernel(const float* __restrict__ wsf, float* __restrict__ out) {
    __shared__ uint4 xs[2][4 * 162 * 2];   // 41472 B
    __shared__ uint4 wsh[2][1152];         // 36864 B
    __shared__ float bsh[64];
    __shared__ float sst[128];

    int id = blockIdx.x;
    int b = id & 15;
    int bx = id >> 4;                      // 0..79
    int y0 = bx * 2;
    int t = threadIdx.x;
    int wv = t >> 6;
    int lane = t & 63;
    int l31 = lane & 31;
    int l5 = lane >> 5;
    int c2h = wv & 1;
    int rw = wv >> 1;

    if (t < 64) bsh[t] = wsf[WS_BIAS + b * 64 + t];
    if (t >= 64 && t < 192) sst[t - 64] = 0.f;
    // halo cols (0,161) x 4 rows x 2 p x 2 chunk-bufs = 32 units
    if (t >= 192 && t < 224) {
        int q = t - 192; int bq = q >> 4; q &= 15;
        int r = q >> 2, side = (q >> 1) & 1, p = q & 1;
        xs[bq][(r * 162 + side * 161) * 2 + p] = make_uint4(0, 0, 0, 0);
    }
    int rbad = (bx == 0) ? 0 : (bx == 79 ? 3 : -1);
    if (rbad >= 0) {
        for (int i = t; i < 640; i += 256)
            xs[i / 320][(rbad * 162 + 1) * 2 + (i % 320)] = make_uint4(0, 0, 0, 0);
    }

    const uint4* weff = (const uint4*)(wsf + WS_WEFF) + (size_t)b * 4608;
    const uint4* xbf  = (const uint4*)(wsf + WS_XBF);

    f32x16 acc[5];
    #pragma unroll
    for (int j = 0; j < 5; ++j)
        #pragma unroll
        for (int r = 0; r < 16; ++r) acc[j][r] = 0.f;

    int c2 = c2h * 32 + l31;
    int aswz = (l31 >> 2) & 1;
    for (int ph = 0; ph < 2; ++ph) {
        __syncthreads();    // previous compute done -> safe to overwrite buffers
        #pragma unroll
        for (int c = 0; c < 2; ++c) {
            int cc = 2 * ph + c;
            for (int i = wv; i < 18; i += 4)
                gload16(weff + (size_t)cc * 1152 + i * 64 + lane, (char*)&wsh[c][0] + i * 1024);
            for (int i = wv; i < 20; i += 4) {
                int r = i / 5, seg = i % 5;
                int gy = y0 - 1 + r;
                if (gy >= 0 && gy < HH)
                    gload16(xbf + (((size_t)b * 4 + cc) * 160 + gy) * 320 + seg * 64 + lane,
                            (char*)&xs[c][0] + ((r * 162 + 1) * 2 + seg * 64) * 16);
            }
        }
        __syncthreads();    // loads drained (compiler emits vmcnt(0) before barrier)

        #pragma unroll
        for (int uv = 0; uv < 9; ++uv) {
            bf16x8 a0 = *(bf16x8*)&wsh[0][(uv * 64 + c2) * 2 + (l5 ^ aswz)];
            bf16x8 a1 = *(bf16x8*)&wsh[1][(uv * 64 + c2) * 2 + (l5 ^ aswz)];
            int xr = rw + uv / 3;
            int v = uv % 3;
            #pragma unroll
            for (int j = 0; j < 5; ++j) {
                int col = j * 32 + l31 + v;
                int bz = (xr * 162 + col) * 2 + (l5 ^ (((col + 3) >> 2) & 1));
                bf16x8 bb0 = *(bf16x8*)&xs[0][bz];
                bf16x8 bb1 = *(bf16x8*)&xs[1][bz];
                acc[j] = __builtin_amdgcn_mfma_f32_32x32x16_bf16(a0, bb0, acc[j], 0, 0, 0);
                acc[j] = __builtin_amdgcn_mfma_f32_32x32x16_bf16(a1, bb1, acc[j], 0, 0, 0);
            }
        }
    }

    // ---- epilogue: bias, store (fp32 out or bf16 obf), BN partials ----
    float* outb = out + (size_t)b * C2 * HWSZ + (size_t)(y0 + rw) * WW;
    unsigned short* obfb = (unsigned short*)((float*)wsf + WS_OBF)
                         + (size_t)b * C2 * HWSZ + (size_t)(y0 + rw) * WW;
    int cb = c2h * 32 + 4 * l5;
    float sr[16], qr[16];
    #pragma unroll
    for (int r = 0; r < 16; ++r) {
        int c2r = cb + (r & 3) + 8 * (r >> 2);
        float bias = bsh[c2r];
        float s = 0.f, q = 0.f;
        #pragma unroll
        for (int j = 0; j < 5; ++j) {
            float v = acc[j][r] + bias;
            if (OBF) obfb[(size_t)c2r * HWSZ + j * 32 + l31] = f2bf(v);
            else     outb[(size_t)c2r * HWSZ + j * 32 + l31] = v;
            s += v;
            q = fmaf(v, v, q);
        }
        sr[r] = s; qr[r] = q;
    }
    #pragma unroll
    for (int k = 0; k < 4; ++k) {
        int m = 1 << k, n = 8 >> k;
        #pragma unroll
        for (int i = 0; i < 8; ++i) {
            if (i < n) {
                float ks = (l31 & m) ? sr[i + n] : sr[i];
                float ss = (l31 & m) ? sr[i] : sr[i + n];
                sr[i] = ks + __shfl_xor(ss, m, 64);
                float kq = (l31 & m) ? qr[i + n] : qr[i];
                float sq = (l31 & m) ? qr[i] : qr[i + n];
                qr[i] = kq + __shfl_xor(sq, m, 64);
            }
        }
    }
    sr[0] += __shfl_xor(sr[0], 16, 64);
    qr[0] += __shfl_xor(qr[0], 16, 64);
    if (l31 < 16) {
        int rf = ((l31 & 1) << 3) | ((l31 & 2) << 1) | ((l31 & 4) >> 1) | ((l31 & 8) >> 3);
        int c2r = cb + (rf & 3) + 8 * (rf >> 2);
        atomicAdd(&sst[c2r], sr[0]);
        atomicAdd(&sst[64 + c2r], qr[0]);
    }
    __syncthreads();
    if (t < 128) {
        int slot = id & (NSLOT - 1);
        atomicAdd((float*)wsf + WS_STATS + slot * 128 + t, sst[t]);
    }
}

// ---------------- Kernel 6: BN finalize + apply + SiLU (reads obf bf16 or out fp32) ----------------
template<int OBF>
__global__ void bnact_kernel(float* __restrict__ out, const float* __restrict__ ws,
                             const float* __restrict__ go, const float* __restrict__ bo) {
    __shared__ float sc[64], sh[64];
    if (threadIdx.x < 64) {
        int c = threadIdx.x;
        float s = 0.f, q = 0.f;
        #pragma unroll
        for (int sl = 0; sl < NSLOT; sl++) {
            s += ws[WS_STATS + sl * 128 + c];
            q += ws[WS_STATS + sl * 128 + 64 + c];
        }
        float mu  = s * (1.0f / (float)NPB);
        float var = q * (1.0f / (float)NPB) - mu * mu;
        float scale = go[c] * rsqrtf(var + EPS);
        sc[c] = scale;
        sh[c] = bo[c] - mu * scale;
    }
    __syncthreads();
    const unsigned short* obf = (const unsigned short*)(ws + WS_OBF);
    const int n4 = BB * C2 * HWSZ / 4;
    for (int i = blockIdx.x * blockDim.x + threadIdx.x; i < n4; i += gridDim.x * blockDim.x) {
        float4 v;
        if (OBF) {
            ushort4 u = ((const ushort4*)obf)[i];
            v.x = __uint_as_float((unsigned)u.x << 16);
            v.y = __uint_as_float((unsigned)u.y << 16);
            v.z = __uint_as_float((unsigned)u.z << 16);
            v.w = __uint_as_float((unsigned)u.w << 16);
        } else {
            v = ((float4*)out)[i];
        }
        int c = ((i * 4) / HWSZ) & 63;
        float s = sc[c], h = sh[c];
        v.x = v.x * s + h; v.y = v.y * s + h; v.z = v.z * s + h; v.w = v.w * s + h;
        v.x = v.x / (1.f + __expf(-v.x));
        v.y = v.y / (1.f + __expf(-v.y));
        v.z = v.z / (1.f + __expf(-v.z));
        v.w = v.w / (1.f + __expf(-v.w));
        ((float4*)out)[i] = v;
    }
}

extern "C" void kernel_launch(void* const* d_in, const int* in_sizes, int n_in,
                              void* d_out, int out_size, void* d_ws, size_t ws_size,
                              hipStream_t stream) {
    const float* x   = (const float*)d_in[0];
    const float* Wk  = (const float*)d_in[1];
    const float* bk  = (const float*)d_in[2];
    const float* Wfc = (const float*)d_in[3];
    const float* gh  = (const float*)d_in[4];
    const float* bh  = (const float*)d_in[5];
    const float* Wf  = (const float*)d_in[6];
    const float* bf  = (const float*)d_in[7];
    const float* Wsm = (const float*)d_in[8];
    const float* bs  = (const float*)d_in[9];
    const float* Wc  = (const float*)d_in[10];
    const float* bc  = (const float*)d_in[11];
    const float* Ww  = (const float*)d_in[12];
    const float* bw  = (const float*)d_in[13];
    const float* go  = (const float*)d_in[14];
    const float* bo  = (const float*)d_in[15];
    float* out = (float*)d_out;
    float* ws  = (float*)d_ws;

    bool use_obf = (ws_size >= WS_NEED_BYTES);

    xprep_kernel<<<dim3(40, 64), dim3(256), 0, stream>>>(x, ws);
    attn_kernel<<<dim3(1), dim3(256), 0, stream>>>(ws, Wfc, gh, bh, Wf, bf, Wsm, bs, Wc, bc, Ww, bw, bk);
    wprep_kernel<<<dim3(18, 16), dim3(256), 0, stream>>>(Wk, ws);
    if (use_obf) {
        conv_kernel<1><<<dim3(1280), dim3(256), 0, stream>>>(ws, out);
        bnact_kernel<1><<<dim3(2048), dim3(256), 0, stream>>>(out, ws, go, bo);
    } else {
        conv_kernel<0><<<dim3(1280), dim3(256), 0, stream>>>(ws, out);
        bnact_kernel<0><<<dim3(2048), dim3(256), 0, stream>>>(out, ws, go, bo);
    }
}

// Round 17
// 129.845 us; speedup vs baseline: 1.0226x; 1.0226x over previous
//
#include <hip/hip_runtime.h>
#include <math.h>

#define BB 16
#define C1 64
#define C2 64
#define HH 160
#define WW 160
#define KK 4
#define HID 16
#define EPS 1e-5f
#define HWSZ (HH*WW)          // 25600
#define NPB (BB*HWSZ)         // 409600 per-channel element count

// ws layout (float offsets)
#define WS_AF    1024         // 1024
#define WS_AC    2048         // 1024
#define WS_AS    3072         // 144
#define WS_AW    3216         // 64
#define WS_BIAS  3280         // 1024
#define WS_STATS 4432         // NSLOT*128 = 4096
#define NSLOT    32
#define WS_PART  8704         // 64*40*16 = 40960 pool partials
#define WS_WEFF  53760        // bf16 image: 16 * 4608 uint4 = 294912 floats
#define WS_XBF   348672       // bf16 x image: 64*160*320 uint4 = 13,107,200 floats
#define WS_OBF   13455872     // bf16 conv-out image: 26,214,400 bf16
#define WS_NEED_BYTES 106252288ULL

typedef __attribute__((ext_vector_type(8)))  short bf16x8;
typedef __attribute__((ext_vector_type(16))) float f32x16;

__device__ __forceinline__ unsigned short f2bf(float f) {
    unsigned int u = __float_as_uint(f);
    unsigned int r = (u + 0x7FFFu + ((u >> 16) & 1u)) >> 16;
    return (unsigned short)r;
}

__device__ __forceinline__ void gload16(const void* g, void* l) {
    __builtin_amdgcn_global_load_lds(
        (const __attribute__((address_space(1))) unsigned int*)g,
        (__attribute__((address_space(3))) unsigned int*)l, 16, 0, 0);
}

// ---------------- Kernel 0: x -> bf16 channels-last image + pool partials ----------------
__global__ __launch_bounds__(256) void xprep_kernel(const float* __restrict__ x,
                                                    float* __restrict__ ws) {
    __shared__ float lds[10240];        // 2560 float4 granules, 40 KB
    int bcc = blockIdx.y;
    int rg = blockIdx.x;
    int t = threadIdx.x;

    const float* src = x + (size_t)bcc * 16 * HWSZ + (size_t)rg * 4 * WW;
    float4* l4 = (float4*)lds;
    #pragma unroll
    for (int i = 0; i < 10; ++i) {
        int g = i * 256 + t;
        int ch = g / 160, rem = g - ch * 160;
        l4[g] = *(const float4*)(src + (size_t)ch * HWSZ + rem * 4);
    }
    __syncthreads();

    {
        int ch = t >> 4, j = t & 15;
        float s = 0.f;
        #pragma unroll
        for (int m = 0; m < 40; ++m) s += lds[ch * 640 + j + 16 * m];
        #pragma unroll
        for (int o = 8; o > 0; o >>= 1) s += __shfl_down(s, o, 16);
        if (j == 0) ws[WS_PART + ((size_t)bcc * 40 + rg) * 16 + ch] = s;
    }

    uint4* dst = (uint4*)(ws + WS_XBF) + ((size_t)bcc * 160 + rg * 4) * 320;
    #pragma unroll
    for (int i = 0; i < 5; ++i) {
        int u = i * 256 + t;
        int row = u / 320, rem = u - row * 320;
        int col = rem >> 1, p = rem & 1;
        int h = p ^ ((col >> 2) & 1) ^ 1;
        union { uint4 q; unsigned short us[8]; } pk;
        #pragma unroll
        for (int k = 0; k < 8; ++k)
            pk.us[k] = f2bf(lds[(h * 8 + k) * 640 + row * 160 + col]);
        dst[u] = pk.q;
    }
}

// ---------------- Kernel 2: attention MLP (single block) ----------------
__global__ void attn_kernel(float* __restrict__ ws,
    const float* __restrict__ Wfc, const float* __restrict__ gh, const float* __restrict__ bh,
    const float* __restrict__ Wf,  const float* __restrict__ bf,
    const float* __restrict__ Wsm, const float* __restrict__ bs,
    const float* __restrict__ Wc,  const float* __restrict__ bc,
    const float* __restrict__ Ww,  const float* __restrict__ bw,
    const float* __restrict__ bk) {
    __shared__ float ctxs[16][64];
    __shared__ float hs[16][16];
    __shared__ float aw[16][4];
    int t = threadIdx.x;

    #pragma unroll
    for (int q = 0; q < 4; ++q) {
        int idx = t * 4 + q;
        int b = idx >> 6, c1 = idx & 63;
        const float* pp = ws + WS_PART + ((size_t)(b * 4 + (c1 >> 4)) * 40) * 16 + (c1 & 15);
        float s = 0.f;
        #pragma unroll
        for (int rg = 0; rg < 40; ++rg) s += pp[rg * 16];
        ctxs[b][c1] = s * (1.0f / (float)HWSZ);
    }
    __syncthreads();
    {
        int b = t >> 4, j = t & 15;
        const float* wr = Wfc + j * 64;
        float s = 0.f;
        #pragma unroll
        for (int c = 0; c < 64; c++) s += ctxs[b][c] * wr[c];
        hs[b][j] = s;
    }
    __syncthreads();
    if (t < 16) {
        int j = t;
        float mu = 0.f;
        #pragma unroll
        for (int b = 0; b < 16; b++) mu += hs[b][j];
        mu *= (1.f / 16.f);
        float vr = 0.f;
        #pragma unroll
        for (int b = 0; b < 16; b++) { float d = hs[b][j] - mu; vr += d * d; }
        vr *= (1.f / 16.f);
        float sc = gh[j] * rsqrtf(vr + EPS);
        float sh = bh[j] - mu * sc;
        #pragma unroll
        for (int b = 0; b < 16; b++) {
            float v = hs[b][j] * sc + sh;
            hs[b][j] = v > 0.f ? v : 0.f;
        }
    }
    __syncthreads();
    if (t < 16) {
        int b = t;
        float l[4]; float mx = -1e30f;
        #pragma unroll
        for (int k = 0; k < 4; k++) {
            float s = bw[k];
            #pragma unroll
            for (int j = 0; j < 16; j++) s += hs[b][j] * Ww[k * 16 + j];
            l[k] = s; mx = fmaxf(mx, s);
        }
        float den = 0.f;
        #pragma unroll
        for (int k = 0; k < 4; k++) { l[k] = expf(l[k] - mx); den += l[k]; }
        float r = 1.f / den;
        #pragma unroll
        for (int k = 0; k < 4; k++) { float v = l[k] * r; aw[b][k] = v; ws[WS_AW + b * 4 + k] = v; }
    }
    #pragma unroll
    for (int q = 0; q < 4; q++) {
        int idx = t * 4 + q;
        int b = idx >> 6, c2 = idx & 63;
        float sf = bf[c2], sc2 = bc[c2];
        #pragma unroll
        for (int j = 0; j < 16; j++) {
            float hv = hs[b][j];
            sf  += hv * Wf[c2 * 16 + j];
            sc2 += hv * Wc[c2 * 16 + j];
        }
        ws[WS_AF + idx] = 1.f / (1.f + expf(-sf));
        ws[WS_AC + idx] = 1.f / (1.f + expf(-sc2));
    }
    if (t < 144) {
        int b = t / 9, uv = t % 9;
        float s = bs[uv];
        #pragma unroll
        for (int j = 0; j < 16; j++) s += hs[b][j] * Wsm[uv * 16 + j];
        ws[WS_AS + t] = 1.f / (1.f + expf(-s));
    }
    __syncthreads();
    #pragma unroll
    for (int q = 0; q < 4; q++) {
        int idx = t * 4 + q;
        int b = idx >> 6, c2 = idx & 63;
        float s = 0.f;
        #pragma unroll
        for (int k = 0; k < 4; k++) s += aw[b][k] * bk[k * 64 + c2];
        ws[WS_BIAS + idx] = s;
    }
    for (int i = t; i < NSLOT * 128; i += 256) ws[WS_STATS + i] = 0.f;
}

// ---------------- Kernel 3: effective weights -> bf16 image ----------------
__global__ void wprep_kernel(const float* __restrict__ Wk, float* __restrict__ ws) {
    int b = blockIdx.y;
    int tid = blockIdx.x * 256 + threadIdx.x;   // < 4608
    int h = tid & 1;
    int c2 = (tid >> 1) & 63;
    int g = tid >> 7;          // 0..35
    int uv = g % 9;
    int chunk = g / 9;
    const float* awp = ws + WS_AW + b * 4;
    float aw0 = awp[0], aw1 = awp[1], aw2 = awp[2], aw3 = awp[3];
    float af = ws[WS_AF + b * 64 + c2];
    float as_ = ws[WS_AS + b * 9 + uv];
    union { uint4 q; unsigned short u[8]; } pk;
    #pragma unroll
    for (int j = 0; j < 8; ++j) {
        int c1 = chunk * 16 + h * 8 + j;
        const float* wp = Wk + (size_t)(c2 * 64 + c1) * 9 + uv;
        float s = aw0 * wp[0] + aw1 * wp[64 * 64 * 9] + aw2 * wp[2 * 64 * 64 * 9] + aw3 * wp[3 * 64 * 64 * 9];
        float w = s * af * ws[WS_AC + b * 64 + c1] * as_;
        pk.u[j] = f2bf(w);
    }
    int unit = ((chunk * 9 + uv) * 64 + c2) * 2 + (h ^ ((c2 >> 2) & 1));
    ((uint4*)(ws + WS_WEFF))[(size_t)b * 4608 + unit] = pk.q;
}

// ---------------- Kernel 4: MFMA conv — 1-wave blocks, zero barriers ----------------
// Grid 5120: b = id&15 (XCD locality); rem = id>>4; y = rem>>1 (row); c2h = rem&1.
// Wave owns 1 row x 32 c2 x 160 px (acc[5]); private 3-row x LDS slice (15.5 KB,
// global_load_lds + per-wave vmcnt — NO __syncthreads); A-frags global->VGPR.
// 8+ independent waves/CU at staggered phases hide each other's stage latency.
template<int OBF>
__launch_bounds__(64, 2)
__global__ void conv_kernel(const float* __restrict__ wsf, float* __restrict__ out) {
    __shared__ uint4 xs[3][324];           // 15552 B, private to this wave

    int id = blockIdx.x;
    int b = id & 15;
    int rem = id >> 4;
    int y = rem >> 1;                      // 0..159
    int c2h = rem & 1;
    int lane = threadIdx.x;
    int l31 = lane & 31;
    int l5 = lane >> 5;

    // halo cols (0,161) x 3 rows: units {0,1,322,323}
    if (lane < 12) {
        int r = lane >> 2, q = lane & 3;
        xs[r][(q >> 1) * 322 + (q & 1)] = make_uint4(0, 0, 0, 0);
    }
    // OOB rows at image edges
    if (y == 0)   for (int i = lane; i < 324; i += 64) xs[0][i] = make_uint4(0, 0, 0, 0);
    if (y == 159) for (int i = lane; i < 324; i += 64) xs[2][i] = make_uint4(0, 0, 0, 0);

    const char*  weffb = (const char*)(wsf + WS_WEFF) + (size_t)b * 73728;
    const uint4* xbf   = (const uint4*)(wsf + WS_XBF);

    int c2 = c2h * 32 + l31;
    int a_off = (c2 * 2 + (l5 ^ ((c2 >> 2) & 1))) * 16;   // R13/R14-validated

    f32x16 acc[5];
    #pragma unroll
    for (int j = 0; j < 5; ++j)
        #pragma unroll
        for (int r = 0; r < 16; ++r) acc[j][r] = 0.f;

    for (int cc = 0; cc < 4; ++cc) {
        // stage private x rows (15 x 1KB gload_lds)
        const uint4* xcc = xbf + ((size_t)(b * 4 + cc) * 160) * 320;
        #pragma unroll
        for (int u = 0; u < 3; ++u) {
            int gy = y - 1 + u;
            if (gy >= 0 && gy < HH) {
                const uint4* src = xcc + gy * 320 + lane;
                #pragma unroll
                for (int seg = 0; seg < 5; ++seg)
                    gload16(src + seg * 64, (char*)&xs[u][2] + seg * 1024);
            }
        }
        // A fragments global->VGPR (L2-resident)
        const char* wrow = weffb + cc * 18432;
        bf16x8 av[9];
        #pragma unroll
        for (int uv = 0; uv < 9; ++uv)
            av[uv] = *(const bf16x8*)(wrow + uv * 2048 + a_off);

        asm volatile("s_waitcnt vmcnt(0) lgkmcnt(0)" ::: "memory");
        __builtin_amdgcn_sched_barrier(0);

        #pragma unroll
        for (int uv = 0; uv < 9; ++uv) {
            int u = uv / 3, v = uv % 3;
            #pragma unroll
            for (int j = 0; j < 5; ++j) {
                int col = j * 32 + l31 + v;
                bf16x8 bb = *(bf16x8*)&xs[u][col * 2 + (l5 ^ (((col + 3) >> 2) & 1))];
                acc[j] = __builtin_amdgcn_mfma_f32_32x32x16_bf16(av[uv], bb, acc[j], 0, 0, 0);
            }
        }
        // all LDS reads retired before next phase's DMA overwrites
        asm volatile("s_waitcnt lgkmcnt(0)" ::: "memory");
        __builtin_amdgcn_sched_barrier(0);
    }

    // ---- epilogue: bias, store (bf16 obf or fp32), BN partials ----
    float* outb = out + (size_t)b * C2 * HWSZ + (size_t)y * WW;
    unsigned short* obfb = (unsigned short*)((float*)wsf + WS_OBF)
                         + (size_t)b * C2 * HWSZ + (size_t)y * WW;
    int cb = c2h * 32 + 4 * l5;
    float sr[16], qr[16];
    #pragma unroll
    for (int r = 0; r < 16; ++r) {
        int c2r = cb + (r & 3) + 8 * (r >> 2);
        float bias = wsf[WS_BIAS + b * 64 + c2r];
        float s = 0.f, q = 0.f;
        #pragma unroll
        for (int j = 0; j < 5; ++j) {
            float v = acc[j][r] + bias;
            if (OBF) obfb[(size_t)c2r * HWSZ + j * 32 + l31] = f2bf(v);
            else     outb[(size_t)c2r * HWSZ + j * 32 + l31] = v;
            s += v;
            q = fmaf(v, v, q);
        }
        sr[r] = s; qr[r] = q;
    }
    #pragma unroll
    for (int k = 0; k < 4; ++k) {
        int m = 1 << k, n = 8 >> k;
        #pragma unroll
        for (int i = 0; i < 8; ++i) {
            if (i < n) {
                float ks = (l31 & m) ? sr[i + n] : sr[i];
                float ss = (l31 & m) ? sr[i] : sr[i + n];
                sr[i] = ks + __shfl_xor(ss, m, 64);
                float kq = (l31 & m) ? qr[i + n] : qr[i];
                float sq = (l31 & m) ? qr[i] : qr[i + n];
                qr[i] = kq + __shfl_xor(sq, m, 64);
            }
        }
    }
    sr[0] += __shfl_xor(sr[0], 16, 64);
    qr[0] += __shfl_xor(qr[0], 16, 64);
    if (l31 < 16) {
        int rf = ((l31 & 1) << 3) | ((l31 & 2) << 1) | ((l31 & 4) >> 1) | ((l31 & 8) >> 3);
        int c2r = cb + (rf & 3) + 8 * (rf >> 2);
        float* st = (float*)wsf + WS_STATS + (size_t)(id & (NSLOT - 1)) * 128;
        atomicAdd(&st[c2r], sr[0]);
        atomicAdd(&st[64 + c2r], qr[0]);
    }
}

// ---------------- Kernel 6: BN finalize + apply + SiLU ----------------
template<int OBF>
__global__ void bnact_kernel(float* __restrict__ out, const float* __restrict__ ws,
                             const float* __restrict__ go, const float* __restrict__ bo) {
    __shared__ float sc[64], sh[64];
    if (threadIdx.x < 64) {
        int c = threadIdx.x;
        float s = 0.f, q = 0.f;
        #pragma unroll
        for (int sl = 0; sl < NSLOT; sl++) {
            s += ws[WS_STATS + sl * 128 + c];
            q += ws[WS_STATS + sl * 128 + 64 + c];
        }
        float mu  = s * (1.0f / (float)NPB);
        float var = q * (1.0f / (float)NPB) - mu * mu;
        float scale = go[c] * rsqrtf(var + EPS);
        sc[c] = scale;
        sh[c] = bo[c] - mu * scale;
    }
    __syncthreads();
    const unsigned short* obf = (const unsigned short*)(ws + WS_OBF);
    const int n4 = BB * C2 * HWSZ / 4;
    for (int i = blockIdx.x * blockDim.x + threadIdx.x; i < n4; i += gridDim.x * blockDim.x) {
        float4 v;
        if (OBF) {
            ushort4 u = ((const ushort4*)obf)[i];
            v.x = __uint_as_float((unsigned)u.x << 16);
            v.y = __uint_as_float((unsigned)u.y << 16);
            v.z = __uint_as_float((unsigned)u.z << 16);
            v.w = __uint_as_float((unsigned)u.w << 16);
        } else {
            v = ((float4*)out)[i];
        }
        int c = ((i * 4) / HWSZ) & 63;
        float s = sc[c], h = sh[c];
        v.x = v.x * s + h; v.y = v.y * s + h; v.z = v.z * s + h; v.w = v.w * s + h;
        v.x = v.x / (1.f + __expf(-v.x));
        v.y = v.y / (1.f + __expf(-v.y));
        v.z = v.z / (1.f + __expf(-v.z));
        v.w = v.w / (1.f + __expf(-v.w));
        ((float4*)out)[i] = v;
    }
}

extern "C" void kernel_launch(void* const* d_in, const int* in_sizes, int n_in,
                              void* d_out, int out_size, void* d_ws, size_t ws_size,
                              hipStream_t stream) {
    const float* x   = (const float*)d_in[0];
    const float* Wk  = (const float*)d_in[1];
    const float* bk  = (const float*)d_in[2];
    const float* Wfc = (const float*)d_in[3];
    const float* gh  = (const float*)d_in[4];
    const float* bh  = (const float*)d_in[5];
    const float* Wf  = (const float*)d_in[6];
    const float* bf  = (const float*)d_in[7];
    const float* Wsm = (const float*)d_in[8];
    const float* bs  = (const float*)d_in[9];
    const float* Wc  = (const float*)d_in[10];
    const float* bc  = (const float*)d_in[11];
    const float* Ww  = (const float*)d_in[12];
    const float* bw  = (const float*)d_in[13];
    const float* go  = (const float*)d_in[14];
    const float* bo  = (const float*)d_in[15];
    float* out = (float*)d_out;
    float* ws  = (float*)d_ws;

    bool use_obf = (ws_size >= WS_NEED_BYTES);

    xprep_kernel<<<dim3(40, 64), dim3(256), 0, stream>>>(x, ws);
    attn_kernel<<<dim3(1), dim3(256), 0, stream>>>(ws, Wfc, gh, bh, Wf, bf, Wsm, bs, Wc, bc, Ww, bw, bk);
    wprep_kernel<<<dim3(18, 16), dim3(256), 0, stream>>>(Wk, ws);
    if (use_obf) {
        conv_kernel<1><<<dim3(5120), dim3(64), 0, stream>>>(ws, out);
        bnact_kernel<1><<<dim3(2048), dim3(256), 0, stream>>>(out, ws, go, bo);
    } else {
        conv_kernel<0><<<dim3(5120), dim3(64), 0, stream>>>(ws, out);
        bnact_kernel<0><<<dim3(2048), dim3(256), 0, stream>>>(out, ws, go, bo);
    }
}

// Round 18
// 124.480 us; speedup vs baseline: 1.0666x; 1.0431x over previous
//
#include <hip/hip_runtime.h>
#include <math.h>

#define BB 16
#define C1 64
#define C2 64
#define HH 160
#define WW 160
#define KK 4
#define HID 16
#define EPS 1e-5f
#define HWSZ (HH*WW)          // 25600
#define NPB (BB*HWSZ)         // 409600 per-channel element count

// ws layout (float offsets)
#define WS_BIAS  3280         // 1024
#define WS_STATS 4432         // NSLOT*128 = 4096
#define NSLOT    32
#define WS_PART  8704         // 64*40*16 = 40960 pool partials
#define WS_WEFF  53760        // bf16 image: 16 * 4608 uint4 = 294912 floats
#define WS_XBF   348672       // bf16 x image: 64*160*320 uint4 = 13,107,200 floats
#define WS_OBF   13455872     // bf16 conv-out image: 26,214,400 bf16
#define WS_NEED_BYTES 106252288ULL

typedef __attribute__((ext_vector_type(8)))  short bf16x8;
typedef __attribute__((ext_vector_type(16))) float f32x16;

__device__ __forceinline__ unsigned short f2bf(float f) {
    unsigned int u = __float_as_uint(f);
    unsigned int r = (u + 0x7FFFu + ((u >> 16) & 1u)) >> 16;
    return (unsigned short)r;
}

__device__ __forceinline__ void gload16(const void* g, void* l) {
    __builtin_amdgcn_global_load_lds(
        (const __attribute__((address_space(1))) unsigned int*)g,
        (__attribute__((address_space(3))) unsigned int*)l, 16, 0, 0);
}

// ---------------- Kernel 0: x -> bf16 channels-last image + pool partials ----------------
__global__ __launch_bounds__(256) void xprep_kernel(const float* __restrict__ x,
                                                    float* __restrict__ ws) {
    __shared__ float lds[10240];        // 2560 float4 granules, 40 KB
    int bcc = blockIdx.y;
    int rg = blockIdx.x;
    int t = threadIdx.x;

    const float* src = x + (size_t)bcc * 16 * HWSZ + (size_t)rg * 4 * WW;
    float4* l4 = (float4*)lds;
    #pragma unroll
    for (int i = 0; i < 10; ++i) {
        int g = i * 256 + t;
        int ch = g / 160, rem = g - ch * 160;
        l4[g] = *(const float4*)(src + (size_t)ch * HWSZ + rem * 4);
    }
    __syncthreads();

    {
        int ch = t >> 4, j = t & 15;
        float s = 0.f;
        #pragma unroll
        for (int m = 0; m < 40; ++m) s += lds[ch * 640 + j + 16 * m];
        #pragma unroll
        for (int o = 8; o > 0; o >>= 1) s += __shfl_down(s, o, 16);
        if (j == 0) ws[WS_PART + ((size_t)bcc * 40 + rg) * 16 + ch] = s;
    }

    uint4* dst = (uint4*)(ws + WS_XBF) + ((size_t)bcc * 160 + rg * 4) * 320;
    #pragma unroll
    for (int i = 0; i < 5; ++i) {
        int u = i * 256 + t;
        int row = u / 320, rem = u - row * 320;
        int col = rem >> 1, p = rem & 1;
        int h = p ^ ((col >> 2) & 1) ^ 1;
        union { uint4 q; unsigned short us[8]; } pk;
        #pragma unroll
        for (int k = 0; k < 8; ++k)
            pk.us[k] = f2bf(lds[(h * 8 + k) * 640 + row * 160 + col]);
        dst[u] = pk.q;
    }
}

// ---------------- Kernel 1: attention (replicated per block) + effective weights ----------------
// grid (18, 16): bx = weff slice, b = blockIdx.y. Every block recomputes the tiny
// attention MLP from PART (L2-resident, deterministic); block bx==0 also writes
// WS_BIAS for its sample and zeroes its WS_STATS slice.
__global__ __launch_bounds__(256) void wprep_kernel(const float* __restrict__ Wk,
    float* __restrict__ ws,
    const float* __restrict__ Wfc, const float* __restrict__ gh, const float* __restrict__ bh,
    const float* __restrict__ Wf,  const float* __restrict__ bf,
    const float* __restrict__ Wsm, const float* __restrict__ bs,
    const float* __restrict__ Wc,  const float* __restrict__ bc,
    const float* __restrict__ Ww,  const float* __restrict__ bw,
    const float* __restrict__ bk) {
    __shared__ float ctxs[16][64];
    __shared__ float hs[16][16];
    __shared__ float afsh[64], acsh[64], assh[9], awsh[4];
    int t = threadIdx.x;
    int b = blockIdx.y;
    int bx = blockIdx.x;

    // ctx for ALL samples (BN over batch needs them)
    #pragma unroll
    for (int q = 0; q < 4; ++q) {
        int idx = t * 4 + q;
        int bb = idx >> 6, c1 = idx & 63;
        const float* pp = ws + WS_PART + ((size_t)(bb * 4 + (c1 >> 4)) * 40) * 16 + (c1 & 15);
        float s = 0.f;
        #pragma unroll
        for (int rg = 0; rg < 40; ++rg) s += pp[rg * 16];
        ctxs[bb][c1] = s * (1.0f / (float)HWSZ);
    }
    __syncthreads();
    {
        int bb = t >> 4, j = t & 15;
        const float* wr = Wfc + j * 64;
        float s = 0.f;
        #pragma unroll
        for (int c = 0; c < 64; c++) s += ctxs[bb][c] * wr[c];
        hs[bb][j] = s;
    }
    __syncthreads();
    if (t < 16) {
        int j = t;
        float mu = 0.f;
        #pragma unroll
        for (int bb = 0; bb < 16; bb++) mu += hs[bb][j];
        mu *= (1.f / 16.f);
        float vr = 0.f;
        #pragma unroll
        for (int bb = 0; bb < 16; bb++) { float d = hs[bb][j] - mu; vr += d * d; }
        vr *= (1.f / 16.f);
        float sc = gh[j] * rsqrtf(vr + EPS);
        float sh = bh[j] - mu * sc;
        #pragma unroll
        for (int bb = 0; bb < 16; bb++) {
            float v = hs[bb][j] * sc + sh;
            hs[bb][j] = v > 0.f ? v : 0.f;
        }
    }
    __syncthreads();
    // heads for THIS sample only
    if (t < 64) {
        float s = bf[t];
        #pragma unroll
        for (int j = 0; j < 16; j++) s += hs[b][j] * Wf[t * 16 + j];
        afsh[t] = 1.f / (1.f + expf(-s));
    } else if (t < 128) {
        int c1 = t - 64;
        float s = bc[c1];
        #pragma unroll
        for (int j = 0; j < 16; j++) s += hs[b][j] * Wc[c1 * 16 + j];
        acsh[c1] = 1.f / (1.f + expf(-s));
    } else if (t < 137) {
        int uv = t - 128;
        float s = bs[uv];
        #pragma unroll
        for (int j = 0; j < 16; j++) s += hs[b][j] * Wsm[uv * 16 + j];
        assh[uv] = 1.f / (1.f + expf(-s));
    } else if (t == 137) {
        float l[4]; float mx = -1e30f;
        #pragma unroll
        for (int k = 0; k < 4; k++) {
            float s = bw[k];
            #pragma unroll
            for (int j = 0; j < 16; j++) s += hs[b][j] * Ww[k * 16 + j];
            l[k] = s; mx = fmaxf(mx, s);
        }
        float den = 0.f;
        #pragma unroll
        for (int k = 0; k < 4; k++) { l[k] = expf(l[k] - mx); den += l[k]; }
        float r = 1.f / den;
        #pragma unroll
        for (int k = 0; k < 4; k++) awsh[k] = l[k] * r;
    }
    __syncthreads();

    // effective weights: tid covers (chunk, uv, c2, h)
    {
        int tid = bx * 256 + t;            // < 4608
        int h = tid & 1;
        int c2 = (tid >> 1) & 63;
        int g = tid >> 7;                  // 0..35
        int uv = g % 9;
        int chunk = g / 9;
        float aw0 = awsh[0], aw1 = awsh[1], aw2 = awsh[2], aw3 = awsh[3];
        float af = afsh[c2];
        float as_ = assh[uv];
        union { uint4 q; unsigned short u[8]; } pk;
        #pragma unroll
        for (int j = 0; j < 8; ++j) {
            int c1 = chunk * 16 + h * 8 + j;
            const float* wp = Wk + (size_t)(c2 * 64 + c1) * 9 + uv;
            float s = aw0 * wp[0] + aw1 * wp[64 * 64 * 9] + aw2 * wp[2 * 64 * 64 * 9] + aw3 * wp[3 * 64 * 64 * 9];
            float w = s * af * acsh[c1] * as_;
            pk.u[j] = f2bf(w);
        }
        int unit = ((chunk * 9 + uv) * 64 + c2) * 2 + (h ^ ((c2 >> 2) & 1));
        ((uint4*)(ws + WS_WEFF))[(size_t)b * 4608 + unit] = pk.q;
    }

    // block bx==0: bias for this sample + zero this sample's stats slice
    if (bx == 0) {
        if (t < 64) {
            float s = 0.f;
            #pragma unroll
            for (int k = 0; k < 4; k++) s += awsh[k] * bk[k * 64 + t];
            ws[WS_BIAS + b * 64 + t] = s;
        }
        ws[WS_STATS + b * 256 + t] = 0.f;  // 16 blocks x 256 = 4096 ✓
    }
}

// ---------------- Kernel 4: MFMA conv — exact R15 winner (proven 60.3 us) ----------------
// Grid 1280: b = id&15 (XCD locality), bx = id>>4 (0..79), 2 output rows.
// 256 thr = 4 waves (rw = wv>>1, c2h = wv&1), acc[5] = 32 c2 x 160 px.
// Single-buffered LDS (39.9 KB), plain 2-barrier loop, 2 blocks/CU.
template<int OBF>
__launch_bounds__(256, 3)
__global__ void conv_kernel(const float* __restrict__ wsf, float* __restrict__ out) {
    __shared__ uint4 xs[4 * 162 * 2];      // 20736 B
    __shared__ uint4 wsh[1152];            // 18432 B
    __shared__ float bsh[64];
    __shared__ float sst[128];

    int id = blockIdx.x;
    int b = id & 15;
    int bx = id >> 4;                      // 0..79
    int y0 = bx * 2;
    int t = threadIdx.x;
    int wv = t >> 6;
    int lane = t & 63;
    int l31 = lane & 31;
    int l5 = lane >> 5;
    int c2h = wv & 1;
    int rw = wv >> 1;

    if (t < 64) bsh[t] = wsf[WS_BIAS + b * 64 + t];
    if (t >= 64 && t < 192) sst[t - 64] = 0.f;
    if (t >= 192 && t < 208) {
        int q = t - 192;
        int r = q >> 2, side = (q >> 1) & 1, p = q & 1;
        xs[(r * 162 + side * 161) * 2 + p] = make_uint4(0, 0, 0, 0);
    }
    int rbad = (bx == 0) ? 0 : (bx == 79 ? 3 : -1);
    if (rbad >= 0) {
        for (int i = t; i < 320; i += 256)
            xs[(rbad * 162 + 1) * 2 + i] = make_uint4(0, 0, 0, 0);
    }

    const uint4* weff = (const uint4*)(wsf + WS_WEFF) + (size_t)b * 4608;
    const uint4* xbf  = (const uint4*)(wsf + WS_XBF);

    f32x16 acc[5];
    #pragma unroll
    for (int j = 0; j < 5; ++j)
        #pragma unroll
        for (int r = 0; r < 16; ++r) acc[j][r] = 0.f;

    int c2 = c2h * 32 + l31;
    int aswz = (l31 >> 2) & 1;
    for (int cc = 0; cc < 4; ++cc) {
        __syncthreads();    // previous compute done -> safe to overwrite buffers
        for (int i = wv; i < 18; i += 4)
            gload16(weff + (size_t)cc * 1152 + i * 64 + lane, (char*)wsh + i * 1024);
        for (int i = wv; i < 20; i += 4) {
            int r = i / 5, seg = i % 5;
            int gy = y0 - 1 + r;
            if (gy >= 0 && gy < HH)
                gload16(xbf + (((size_t)b * 4 + cc) * 160 + gy) * 320 + seg * 64 + lane,
                        (char*)xs + ((r * 162 + 1) * 2 + seg * 64) * 16);
        }
        __syncthreads();    // loads drained (compiler emits vmcnt(0) before barrier)

        #pragma unroll
        for (int uv = 0; uv < 9; ++uv) {
            bf16x8 a = *(bf16x8*)&wsh[(uv * 64 + c2) * 2 + (l5 ^ aswz)];
            int xr = rw + uv / 3;
            int v = uv % 3;
            #pragma unroll
            for (int j = 0; j < 5; ++j) {
                int col = j * 32 + l31 + v;
                bf16x8 bb = *(bf16x8*)&xs[(xr * 162 + col) * 2 + (l5 ^ (((col + 3) >> 2) & 1))];
                acc[j] = __builtin_amdgcn_mfma_f32_32x32x16_bf16(a, bb, acc[j], 0, 0, 0);
            }
        }
    }

    // ---- epilogue: bias, store (fp32 out or bf16 obf), BN partials ----
    float* outb = out + (size_t)b * C2 * HWSZ + (size_t)(y0 + rw) * WW;
    unsigned short* obfb = (unsigned short*)((float*)wsf + WS_OBF)
                         + (size_t)b * C2 * HWSZ + (size_t)(y0 + rw) * WW;
    int cb = c2h * 32 + 4 * l5;
    float sr[16], qr[16];
    #pragma unroll
    for (int r = 0; r < 16; ++r) {
        int c2r = cb + (r & 3) + 8 * (r >> 2);
        float bias = bsh[c2r];
        float s = 0.f, q = 0.f;
        #pragma unroll
        for (int j = 0; j < 5; ++j) {
            float v = acc[j][r] + bias;
            if (OBF) obfb[(size_t)c2r * HWSZ + j * 32 + l31] = f2bf(v);
            else     outb[(size_t)c2r * HWSZ + j * 32 + l31] = v;
            s += v;
            q = fmaf(v, v, q);
        }
        sr[r] = s; qr[r] = q;
    }
    #pragma unroll
    for (int k = 0; k < 4; ++k) {
        int m = 1 << k, n = 8 >> k;
        #pragma unroll
        for (int i = 0; i < 8; ++i) {
            if (i < n) {
                float ks = (l31 & m) ? sr[i + n] : sr[i];
                float ss = (l31 & m) ? sr[i] : sr[i + n];
                sr[i] = ks + __shfl_xor(ss, m, 64);
                float kq = (l31 & m) ? qr[i + n] : qr[i];
                float sq = (l31 & m) ? qr[i] : qr[i + n];
                qr[i] = kq + __shfl_xor(sq, m, 64);
            }
        }
    }
    sr[0] += __shfl_xor(sr[0], 16, 64);
    qr[0] += __shfl_xor(qr[0], 16, 64);
    if (l31 < 16) {
        int rf = ((l31 & 1) << 3) | ((l31 & 2) << 1) | ((l31 & 4) >> 1) | ((l31 & 8) >> 3);
        int c2r = cb + (rf & 3) + 8 * (rf >> 2);
        atomicAdd(&sst[c2r], sr[0]);
        atomicAdd(&sst[64 + c2r], qr[0]);
    }
    __syncthreads();
    if (t < 128) {
        int slot = id & (NSLOT - 1);
        atomicAdd((float*)wsf + WS_STATS + slot * 128 + t, sst[t]);
    }
}

// ---------------- Kernel 6: BN finalize + apply + SiLU ----------------
template<int OBF>
__global__ void bnact_kernel(float* __restrict__ out, const float* __restrict__ ws,
                             const float* __restrict__ go, const float* __restrict__ bo) {
    __shared__ float sc[64], sh[64];
    if (threadIdx.x < 64) {
        int c = threadIdx.x;
        float s = 0.f, q = 0.f;
        #pragma unroll
        for (int sl = 0; sl < NSLOT; sl++) {
            s += ws[WS_STATS + sl * 128 + c];
            q += ws[WS_STATS + sl * 128 + 64 + c];
        }
        float mu  = s * (1.0f / (float)NPB);
        float var = q * (1.0f / (float)NPB) - mu * mu;
        float scale = go[c] * rsqrtf(var + EPS);
        sc[c] = scale;
        sh[c] = bo[c] - mu * scale;
    }
    __syncthreads();
    const unsigned short* obf = (const unsigned short*)(ws + WS_OBF);
    const int n4 = BB * C2 * HWSZ / 4;
    for (int i = blockIdx.x * blockDim.x + threadIdx.x; i < n4; i += gridDim.x * blockDim.x) {
        float4 v;
        if (OBF) {
            ushort4 u = ((const ushort4*)obf)[i];
            v.x = __uint_as_float((unsigned)u.x << 16);
            v.y = __uint_as_float((unsigned)u.y << 16);
            v.z = __uint_as_float((unsigned)u.z << 16);
            v.w = __uint_as_float((unsigned)u.w << 16);
        } else {
            v = ((float4*)out)[i];
        }
        int c = ((i * 4) / HWSZ) & 63;
        float s = sc[c], h = sh[c];
        v.x = v.x * s + h; v.y = v.y * s + h; v.z = v.z * s + h; v.w = v.w * s + h;
        v.x = v.x / (1.f + __expf(-v.x));
        v.y = v.y / (1.f + __expf(-v.y));
        v.z = v.z / (1.f + __expf(-v.z));
        v.w = v.w / (1.f + __expf(-v.w));
        ((float4*)out)[i] = v;
    }
}

extern "C" void kernel_launch(void* const* d_in, const int* in_sizes, int n_in,
                              void* d_out, int out_size, void* d_ws, size_t ws_size,
                              hipStream_t stream) {
    const float* x   = (const float*)d_in[0];
    const float* Wk  = (const float*)d_in[1];
    const float* bk  = (const float*)d_in[2];
    const float* Wfc = (const float*)d_in[3];
    const float* gh  = (const float*)d_in[4];
    const float* bh  = (const float*)d_in[5];
    const float* Wf  = (const float*)d_in[6];
    const float* bf  = (const float*)d_in[7];
    const float* Wsm = (const float*)d_in[8];
    const float* bs  = (const float*)d_in[9];
    const float* Wc  = (const float*)d_in[10];
    const float* bc  = (const float*)d_in[11];
    const float* Ww  = (const float*)d_in[12];
    const float* bw  = (const float*)d_in[13];
    const float* go  = (const float*)d_in[14];
    const float* bo  = (const float*)d_in[15];
    float* out = (float*)d_out;
    float* ws  = (float*)d_ws;

    bool use_obf = (ws_size >= WS_NEED_BYTES);

    xprep_kernel<<<dim3(40, 64), dim3(256), 0, stream>>>(x, ws);
    wprep_kernel<<<dim3(18, 16), dim3(256), 0, stream>>>(Wk, ws, Wfc, gh, bh, Wf, bf, Wsm, bs, Wc, bc, Ww, bw, bk);
    if (use_obf) {
        conv_kernel<1><<<dim3(1280), dim3(256), 0, stream>>>(ws, out);
        bnact_kernel<1><<<dim3(2048), dim3(256), 0, stream>>>(out, ws, go, bo);
    } else {
        conv_kernel<0><<<dim3(1280), dim3(256), 0, stream>>>(ws, out);
        bnact_kernel<0><<<dim3(2048), dim3(256), 0, stream>>>(out, ws, go, bo);
    }
}